// Round 4
// baseline (212.891 us; speedup 1.0000x reference)
//
#include <hip/hip_runtime.h>
#include <hip/hip_cooperative_groups.h>
#include <math.h>

namespace cg = cooperative_groups;

#define Bc 4
#define Lc 48
#define Kc 32
#define Dc 128
#define ROWS (Bc*Lc*Kc)      // 6144
#define GT 512               // threads per block
#define ARENA_F 28800        // floats: 115.2 KB LDS arena -> 1 block/CU

// arena layout (floats):
//  phase1 role0 : sA[0,6144) sT[6144,12288) sB[12288,28672) sBias[28672,28800)
//  phase1 role12: sA[0,12288)               sB[12288,28672) sBias[28672,28800)
//  phase2 attn  : HJ[0,6336) MS[6336,12672) HI[12672,15840) WA[15840,15968)
//                 GM[15968,16096) BT[16096,16224) WT[16224,17376)

// ---------- 3x4 register-tile GEMM (rows rg*3..+2) ----------
__device__ __forceinline__ void gemm3x4(
    const float* __restrict__ sA, const float* __restrict__ sB,
    int rg, int c0, float acc[3][4])
{
    const float* A0 = sA + rg*3*Dc;
    #pragma unroll 8
    for (int k = 0; k < Dc; k += 4) {
        float4 a0 = *(const float4*)(A0 + k);
        float4 a1 = *(const float4*)(A0 + Dc + k);
        float4 a2 = *(const float4*)(A0 + 2*Dc + k);
        float4 b0 = *(const float4*)(sB + (k+0)*Dc + c0);
        float4 b1 = *(const float4*)(sB + (k+1)*Dc + c0);
        float4 b2 = *(const float4*)(sB + (k+2)*Dc + c0);
        float4 b3 = *(const float4*)(sB + (k+3)*Dc + c0);
        float a_[3][4] = {{a0.x,a0.y,a0.z,a0.w},{a1.x,a1.y,a1.z,a1.w},{a2.x,a2.y,a2.z,a2.w}};
        float b_[4][4] = {{b0.x,b0.y,b0.z,b0.w},{b1.x,b1.y,b1.z,b1.w},
                          {b2.x,b2.y,b2.z,b2.w},{b3.x,b3.y,b3.z,b3.w}};
        #pragma unroll
        for (int r = 0; r < 3; ++r)
            #pragma unroll
            for (int c = 0; c < 4; ++c)
                #pragma unroll
                for (int q = 0; q < 4; ++q)
                    acc[r][c] = fmaf(a_[r][q], b_[q][c], acc[r][c]);
    }
}

// ---------- phase 1: the four row-GEMMs, 256 equal-FLOP blocks ----------
// blk 0..127  : role0, 48 rows: t=relu(h@Wm1+bm1) (LDS) -> msg=t@Wm2+bm2
// blk 128..191: role1, 96 rows: hip = h@Wa1[:D] + ba1 (ba2 dropped: softmax-invariant)
// blk 192..255: role2, 96 rows: hjp = h@Wa1[D:]
__device__ __forceinline__ void phase1(
    float* arena, int blk, int tid,
    const float* __restrict__ h,
    const float* __restrict__ Wm1, const float* __restrict__ bm1,
    const float* __restrict__ Wm2, const float* __restrict__ bm2,
    const float* __restrict__ Wa1, const float* __restrict__ ba1,
    float* __restrict__ msg_ws, float* __restrict__ hip_ws,
    float* __restrict__ hjp_ws)
{
    float* sB    = arena + 12288;
    float* sBias = arena + 28672;
    const int rg = tid >> 5;
    const int c0 = (tid & 31) * 4;

    if (blk < 128) {
        float* sA = arena;
        float* sT = arena + 6144;
        const int r0 = blk * 48;
        {
            const float4* src = (const float4*)Wm1;
            float4* dst = (float4*)sB;
            #pragma unroll
            for (int i = 0; i < 8; ++i) dst[tid + i*GT] = src[tid + i*GT];
            const float4* asrc = (const float4*)(h + r0*Dc);
            float4* adst = (float4*)sA;
            #pragma unroll
            for (int i = 0; i < 3; ++i) adst[tid + i*GT] = asrc[tid + i*GT];
            if (tid < 32) ((float4*)sBias)[tid] = ((const float4*)bm1)[tid];
        }
        __syncthreads();

        float acc[3][4] = {};
        gemm3x4(sA, sB, rg, c0, acc);
        #pragma unroll
        for (int r = 0; r < 3; ++r) {
            float4 v;
            v.x = fmaxf(acc[r][0] + sBias[c0+0], 0.f);
            v.y = fmaxf(acc[r][1] + sBias[c0+1], 0.f);
            v.z = fmaxf(acc[r][2] + sBias[c0+2], 0.f);
            v.w = fmaxf(acc[r][3] + sBias[c0+3], 0.f);
            *(float4*)(sT + (rg*3+r)*Dc + c0) = v;
        }
        __syncthreads();   // sB(Wm1) reads done + sT visible
        {
            const float4* src = (const float4*)Wm2;
            float4* dst = (float4*)sB;
            #pragma unroll
            for (int i = 0; i < 8; ++i) dst[tid + i*GT] = src[tid + i*GT];
            if (tid < 32) ((float4*)sBias)[tid] = ((const float4*)bm2)[tid];
        }
        __syncthreads();

        float acc2[3][4] = {};
        gemm3x4(sT, sB, rg, c0, acc2);
        #pragma unroll
        for (int r = 0; r < 3; ++r) {
            float4 v;
            v.x = acc2[r][0] + sBias[c0+0];
            v.y = acc2[r][1] + sBias[c0+1];
            v.z = acc2[r][2] + sBias[c0+2];
            v.w = acc2[r][3] + sBias[c0+3];
            *(float4*)(msg_ws + (r0 + rg*3 + r)*Dc + c0) = v;
        }
    } else {
        const bool role1 = blk < 192;
        const int  r0 = (blk - (role1 ? 128 : 192)) * 96;
        const float* W = role1 ? Wa1 : (Wa1 + Dc*Dc);
        float* outp = role1 ? hip_ws : hjp_ws;
        float* sA = arena;    // 96x128
        {
            const float4* src = (const float4*)W;
            float4* dst = (float4*)sB;
            #pragma unroll
            for (int i = 0; i < 8; ++i) dst[tid + i*GT] = src[tid + i*GT];
            const float4* asrc = (const float4*)(h + r0*Dc);
            float4* adst = (float4*)sA;
            #pragma unroll
            for (int i = 0; i < 6; ++i) adst[tid + i*GT] = asrc[tid + i*GT];
            if (tid < 32)
                ((float4*)sBias)[tid] = role1 ? ((const float4*)ba1)[tid]
                                              : make_float4(0.f, 0.f, 0.f, 0.f);
        }
        __syncthreads();

        const float* A0 = sA + rg*6*Dc;
        float acc[6][4] = {};
        #pragma unroll 2
        for (int k = 0; k < Dc; k += 4) {
            float4 b0 = *(const float4*)(sB + (k+0)*Dc + c0);
            float4 b1 = *(const float4*)(sB + (k+1)*Dc + c0);
            float4 b2 = *(const float4*)(sB + (k+2)*Dc + c0);
            float4 b3 = *(const float4*)(sB + (k+3)*Dc + c0);
            #pragma unroll
            for (int r = 0; r < 6; ++r) {
                float4 a = *(const float4*)(A0 + r*Dc + k);
                acc[r][0] = fmaf(a.w,b3.x,fmaf(a.z,b2.x,fmaf(a.y,b1.x,fmaf(a.x,b0.x,acc[r][0]))));
                acc[r][1] = fmaf(a.w,b3.y,fmaf(a.z,b2.y,fmaf(a.y,b1.y,fmaf(a.x,b0.y,acc[r][1]))));
                acc[r][2] = fmaf(a.w,b3.z,fmaf(a.z,b2.z,fmaf(a.y,b1.z,fmaf(a.x,b0.z,acc[r][2]))));
                acc[r][3] = fmaf(a.w,b3.w,fmaf(a.z,b2.w,fmaf(a.y,b1.w,fmaf(a.x,b0.w,acc[r][3]))));
            }
        }
        #pragma unroll
        for (int r = 0; r < 6; ++r) {
            float4 v;
            v.x = acc[r][0] + sBias[c0+0];
            v.y = acc[r][1] + sBias[c0+1];
            v.z = acc[r][2] + sBias[c0+2];
            v.w = acc[r][3] + sBias[c0+3];
            *(float4*)(outp + (r0 + rg*6 + r)*Dc + c0) = v;
        }
    }
}

// ---------- phase 2: logits + softmax + aggregation + residual + LN ----------
__device__ __forceinline__ void phase2(
    float* arena, int blk, int tid,
    const float* __restrict__ h,
    const float* __restrict__ hip_ws, const float* __restrict__ hjp_ws,
    const float* __restrict__ msg_ws,
    const float* __restrict__ wa2, const float* __restrict__ gamma,
    const float* __restrict__ beta, float* __restrict__ out)
{
    const int b  = blk >> 6;
    const int k  = (blk >> 1) & 31;
    const int i0 = (blk & 1) * 24;

    float* HJ = arena;
    float* MS = arena + 6336;
    float* HI = arena + 12672;
    float* WA = arena + 15840;
    float* GM = arena + 15968;
    float* BT = arena + 16096;
    float* WT = arena + 16224;

    for (int idx = tid; idx < 48*32; idx += GT) {
        const int j = idx >> 5, c4 = (idx & 31) * 4;
        const int g = ((b*Lc + j)*Kc + k)*Dc + c4;
        *(float4*)(HJ + j*132 + c4) = *(const float4*)(hjp_ws + g);
        *(float4*)(MS + j*132 + c4) = *(const float4*)(msg_ws + g);
    }
    for (int idx = tid; idx < 24*32; idx += GT) {
        const int i = idx >> 5, c4 = (idx & 31) * 4;
        const int g = ((b*Lc + i0 + i)*Kc + k)*Dc + c4;
        *(float4*)(HI + i*132 + c4) = *(const float4*)(hip_ws + g);
    }
    if (tid < 32)       ((float4*)WA)[tid]      = ((const float4*)wa2)[tid];
    else if (tid < 64)  ((float4*)GM)[tid - 32] = ((const float4*)gamma)[tid - 32];
    else if (tid < 96)  ((float4*)BT)[tid - 64] = ((const float4*)beta)[tid - 64];
    __syncthreads();

    const int wave = tid >> 6;
    const int lane = tid & 63;
    const int il0  = wave * 3;
    const bool jv  = lane < 48;
    const int  jl  = jv ? lane : 0;

    float s0 = 0.f, s1 = 0.f, s2 = 0.f;
    {
        const float* hj = HJ + jl*132;
        const float* hA = HI + il0*132;
        const float* hB = hA + 132;
        const float* hC = hB + 132;
        #pragma unroll 4
        for (int d = 0; d < Dc; d += 4) {
            const float4 hj4 = *(const float4*)(hj + d);
            const float4 w4  = *(const float4*)(WA + d);
            const float4 a4  = *(const float4*)(hA + d);
            const float4 b4  = *(const float4*)(hB + d);
            const float4 c4  = *(const float4*)(hC + d);
            s0 = fmaf(fmaxf(a4.x + hj4.x, 0.f), w4.x, s0);
            s0 = fmaf(fmaxf(a4.y + hj4.y, 0.f), w4.y, s0);
            s0 = fmaf(fmaxf(a4.z + hj4.z, 0.f), w4.z, s0);
            s0 = fmaf(fmaxf(a4.w + hj4.w, 0.f), w4.w, s0);
            s1 = fmaf(fmaxf(b4.x + hj4.x, 0.f), w4.x, s1);
            s1 = fmaf(fmaxf(b4.y + hj4.y, 0.f), w4.y, s1);
            s1 = fmaf(fmaxf(b4.z + hj4.z, 0.f), w4.z, s1);
            s1 = fmaf(fmaxf(b4.w + hj4.w, 0.f), w4.w, s1);
            s2 = fmaf(fmaxf(c4.x + hj4.x, 0.f), w4.x, s2);
            s2 = fmaf(fmaxf(c4.y + hj4.y, 0.f), w4.y, s2);
            s2 = fmaf(fmaxf(c4.z + hj4.z, 0.f), w4.z, s2);
            s2 = fmaf(fmaxf(c4.w + hj4.w, 0.f), w4.w, s2);
        }
    }

    float sv[3] = { jv ? s0 : -1e30f, jv ? s1 : -1e30f, jv ? s2 : -1e30f };
    #pragma unroll
    for (int q = 0; q < 3; ++q) {
        float m = sv[q];
        #pragma unroll
        for (int off = 32; off; off >>= 1) m = fmaxf(m, __shfl_xor(m, off));
        const float p = jv ? __expf(sv[q] - m) : 0.f;
        float sum = p;
        #pragma unroll
        for (int off = 32; off; off >>= 1) sum += __shfl_xor(sum, off);
        if (jv) WT[(il0 + q)*48 + lane] = p / sum;
    }
    __syncthreads();

    const int d0 = lane * 2;
    float ac[3][2] = {};
    const float* wt0 = WT + il0*48;
    const float* wt1 = wt0 + 48;
    const float* wt2 = wt1 + 48;
    #pragma unroll 4
    for (int j = 0; j < 48; ++j) {
        const float2 m2 = *(const float2*)(MS + j*132 + d0);
        const float wA = wt0[j], wB = wt1[j], wC = wt2[j];
        ac[0][0] = fmaf(wA, m2.x, ac[0][0]); ac[0][1] = fmaf(wA, m2.y, ac[0][1]);
        ac[1][0] = fmaf(wB, m2.x, ac[1][0]); ac[1][1] = fmaf(wB, m2.y, ac[1][1]);
        ac[2][0] = fmaf(wC, m2.x, ac[2][0]); ac[2][1] = fmaf(wC, m2.y, ac[2][1]);
    }
    const float gm0 = GM[d0], gm1 = GM[d0+1], bt0 = BT[d0], bt1 = BT[d0+1];
    #pragma unroll
    for (int q = 0; q < 3; ++q) {
        const int i = i0 + il0 + q;
        const int g = ((b*Lc + i)*Kc + k)*Dc + d0;
        const float2 h2 = *(const float2*)(h + g);
        const float x0 = h2.x + ac[q][0];
        const float x1 = h2.y + ac[q][1];
        float ps = x0 + x1;
        float pq = x0*x0 + x1*x1;
        #pragma unroll
        for (int off = 32; off; off >>= 1) {
            ps += __shfl_xor(ps, off);
            pq += __shfl_xor(pq, off);
        }
        const float mu  = ps * (1.f/128.f);
        const float var = pq * (1.f/128.f) - mu*mu;
        const float rs  = rsqrtf(var + 1e-5f);
        float2 o2;
        o2.x = (x0 - mu)*rs*gm0 + bt0;
        o2.y = (x1 - mu)*rs*gm1 + bt1;
        *(float2*)(out + g) = o2;
    }
}

// ---------- fused cooperative kernel ----------
__global__ __launch_bounds__(GT, 1) void k_fused(
    const float* __restrict__ h,
    const float* __restrict__ Wm1, const float* __restrict__ bm1,
    const float* __restrict__ Wm2, const float* __restrict__ bm2,
    const float* __restrict__ Wa1, const float* __restrict__ ba1,
    const float* __restrict__ wa2, const float* __restrict__ gamma,
    const float* __restrict__ beta,
    float* __restrict__ msg_ws, float* __restrict__ hip_ws,
    float* __restrict__ hjp_ws, float* __restrict__ out)
{
    __shared__ float arena[ARENA_F];
    const int tid = threadIdx.x, blk = blockIdx.x;
    phase1(arena, blk, tid, h, Wm1, bm1, Wm2, bm2, Wa1, ba1,
           msg_ws, hip_ws, hjp_ws);
    __threadfence();           // device-scope release before grid sync
    cg::this_grid().sync();
    phase2(arena, blk, tid, h, hip_ws, hjp_ws, msg_ws, wa2, gamma, beta, out);
}

// ---------- fallback: same bodies as two plain kernels ----------
__global__ __launch_bounds__(GT) void k_p1(
    const float* __restrict__ h,
    const float* __restrict__ Wm1, const float* __restrict__ bm1,
    const float* __restrict__ Wm2, const float* __restrict__ bm2,
    const float* __restrict__ Wa1, const float* __restrict__ ba1,
    float* __restrict__ msg_ws, float* __restrict__ hip_ws,
    float* __restrict__ hjp_ws)
{
    __shared__ float arena[ARENA_F];
    phase1(arena, blockIdx.x, threadIdx.x, h, Wm1, bm1, Wm2, bm2, Wa1, ba1,
           msg_ws, hip_ws, hjp_ws);
}

__global__ __launch_bounds__(GT) void k_p2(
    const float* __restrict__ h,
    const float* __restrict__ hip_ws, const float* __restrict__ hjp_ws,
    const float* __restrict__ msg_ws,
    const float* __restrict__ wa2, const float* __restrict__ gamma,
    const float* __restrict__ beta, float* __restrict__ out)
{
    __shared__ float arena[ARENA_F];
    phase2(arena, blockIdx.x, threadIdx.x, h, hip_ws, hjp_ws, msg_ws,
           wa2, gamma, beta, out);
}

extern "C" void kernel_launch(void* const* d_in, const int* in_sizes, int n_in,
                              void* d_out, int out_size, void* d_ws, size_t ws_size,
                              hipStream_t stream)
{
    const float* h     = (const float*)d_in[0];
    const float* Wm1   = (const float*)d_in[1];
    const float* bm1   = (const float*)d_in[2];
    const float* Wm2   = (const float*)d_in[3];
    const float* bm2   = (const float*)d_in[4];
    const float* Wa1   = (const float*)d_in[5];
    const float* ba1   = (const float*)d_in[6];
    const float* wa2   = (const float*)d_in[7];
    // d_in[8] = ba2: softmax-invariant constant, dropped
    const float* gamma = (const float*)d_in[9];
    const float* beta  = (const float*)d_in[10];

    float* msg_ws = (float*)d_ws;
    float* hip_ws = msg_ws + ROWS*Dc;
    float* hjp_ws = hip_ws + ROWS*Dc;
    float* outp   = (float*)d_out;

    void* args[] = { (void*)&h, (void*)&Wm1, (void*)&bm1, (void*)&Wm2,
                     (void*)&bm2, (void*)&Wa1, (void*)&ba1, (void*)&wa2,
                     (void*)&gamma, (void*)&beta,
                     (void*)&msg_ws, (void*)&hip_ws, (void*)&hjp_ws,
                     (void*)&outp };
    hipError_t e = hipLaunchCooperativeKernel((const void*)k_fused,
                                              dim3(256), dim3(GT),
                                              args, 0, stream);
    if (e != hipSuccess) {
        // deterministic fallback: identical device work, two launches
        hipLaunchKernelGGL(k_p1, dim3(256), dim3(GT), 0, stream,
                           h, Wm1, bm1, Wm2, bm2, Wa1, ba1,
                           msg_ws, hip_ws, hjp_ws);
        hipLaunchKernelGGL(k_p2, dim3(256), dim3(GT), 0, stream,
                           h, hip_ws, hjp_ws, msg_ws, wa2, gamma, beta, outp);
    }
}

// Round 7
// 102.646 us; speedup vs baseline: 2.0740x; 2.0740x over previous
//
#include <hip/hip_runtime.h>
#include <math.h>

#define Bc 4
#define Lc 48
#define Kc 32
#define Dc 128
#define ROWS (Bc*Lc*Kc)      // 6144
#define GT 512               // threads per block
#define ARENA_F 28800        // floats: 115.2 KB -> 1 block/CU (phase1)

// ---------- 3x4 register-tile GEMM (rows rg*3..+2) ----------
__device__ __forceinline__ void gemm3x4(
    const float* __restrict__ sA, const float* __restrict__ sB,
    int rg, int c0, float acc[3][4])
{
    const float* A0 = sA + rg*3*Dc;
    #pragma unroll 8
    for (int k = 0; k < Dc; k += 4) {
        float4 a0 = *(const float4*)(A0 + k);
        float4 a1 = *(const float4*)(A0 + Dc + k);
        float4 a2 = *(const float4*)(A0 + 2*Dc + k);
        float4 b0 = *(const float4*)(sB + (k+0)*Dc + c0);
        float4 b1 = *(const float4*)(sB + (k+1)*Dc + c0);
        float4 b2 = *(const float4*)(sB + (k+2)*Dc + c0);
        float4 b3 = *(const float4*)(sB + (k+3)*Dc + c0);
        float a_[3][4] = {{a0.x,a0.y,a0.z,a0.w},{a1.x,a1.y,a1.z,a1.w},{a2.x,a2.y,a2.z,a2.w}};
        float b_[4][4] = {{b0.x,b0.y,b0.z,b0.w},{b1.x,b1.y,b1.z,b1.w},
                          {b2.x,b2.y,b2.z,b2.w},{b3.x,b3.y,b3.z,b3.w}};
        #pragma unroll
        for (int r = 0; r < 3; ++r)
            #pragma unroll
            for (int c = 0; c < 4; ++c)
                #pragma unroll
                for (int q = 0; q < 4; ++q)
                    acc[r][c] = fmaf(a_[r][q], b_[q][c], acc[r][c]);
    }
}

// ---------- phase 1: the four row-GEMMs, 256 equal-FLOP blocks ----------
// blk 0..127  : role0, 48 rows: t=relu(h@Wm1+bm1) (LDS) -> msg=t@Wm2+bm2
// blk 128..191: role1, 96 rows: hip = h@Wa1[:D] + ba1 (ba2 dropped: softmax-invariant)
// blk 192..255: role2, 96 rows: hjp = h@Wa1[D:]
__global__ __launch_bounds__(GT) void k_p1(
    const float* __restrict__ h,
    const float* __restrict__ Wm1, const float* __restrict__ bm1,
    const float* __restrict__ Wm2, const float* __restrict__ bm2,
    const float* __restrict__ Wa1, const float* __restrict__ ba1,
    float* __restrict__ msg_ws, float* __restrict__ hip_ws,
    float* __restrict__ hjp_ws)
{
    __shared__ float arena[ARENA_F];
    const int tid = threadIdx.x, blk = blockIdx.x;

    float* sB    = arena + 12288;
    float* sBias = arena + 28672;
    const int rg = tid >> 5;
    const int c0 = (tid & 31) * 4;

    if (blk < 128) {
        float* sA = arena;
        float* sT = arena + 6144;
        const int r0 = blk * 48;
        {
            const float4* src = (const float4*)Wm1;
            float4* dst = (float4*)sB;
            #pragma unroll
            for (int i = 0; i < 8; ++i) dst[tid + i*GT] = src[tid + i*GT];
            const float4* asrc = (const float4*)(h + r0*Dc);
            float4* adst = (float4*)sA;
            #pragma unroll
            for (int i = 0; i < 3; ++i) adst[tid + i*GT] = asrc[tid + i*GT];
            if (tid < 32) ((float4*)sBias)[tid] = ((const float4*)bm1)[tid];
        }
        __syncthreads();

        float acc[3][4] = {};
        gemm3x4(sA, sB, rg, c0, acc);
        #pragma unroll
        for (int r = 0; r < 3; ++r) {
            float4 v;
            v.x = fmaxf(acc[r][0] + sBias[c0+0], 0.f);
            v.y = fmaxf(acc[r][1] + sBias[c0+1], 0.f);
            v.z = fmaxf(acc[r][2] + sBias[c0+2], 0.f);
            v.w = fmaxf(acc[r][3] + sBias[c0+3], 0.f);
            *(float4*)(sT + (rg*3+r)*Dc + c0) = v;
        }
        __syncthreads();   // sB(Wm1) reads done + sT visible
        {
            const float4* src = (const float4*)Wm2;
            float4* dst = (float4*)sB;
            #pragma unroll
            for (int i = 0; i < 8; ++i) dst[tid + i*GT] = src[tid + i*GT];
            if (tid < 32) ((float4*)sBias)[tid] = ((const float4*)bm2)[tid];
        }
        __syncthreads();

        float acc2[3][4] = {};
        gemm3x4(sT, sB, rg, c0, acc2);
        #pragma unroll
        for (int r = 0; r < 3; ++r) {
            float4 v;
            v.x = acc2[r][0] + sBias[c0+0];
            v.y = acc2[r][1] + sBias[c0+1];
            v.z = acc2[r][2] + sBias[c0+2];
            v.w = acc2[r][3] + sBias[c0+3];
            *(float4*)(msg_ws + (r0 + rg*3 + r)*Dc + c0) = v;
        }
    } else {
        const bool role1 = blk < 192;
        const int  r0 = (blk - (role1 ? 128 : 192)) * 96;
        const float* W = role1 ? Wa1 : (Wa1 + Dc*Dc);
        float* outp = role1 ? hip_ws : hjp_ws;
        float* sA = arena;    // 96x128
        {
            const float4* src = (const float4*)W;
            float4* dst = (float4*)sB;
            #pragma unroll
            for (int i = 0; i < 8; ++i) dst[tid + i*GT] = src[tid + i*GT];
            const float4* asrc = (const float4*)(h + r0*Dc);
            float4* adst = (float4*)sA;
            #pragma unroll
            for (int i = 0; i < 6; ++i) adst[tid + i*GT] = asrc[tid + i*GT];
            if (tid < 32)
                ((float4*)sBias)[tid] = role1 ? ((const float4*)ba1)[tid]
                                              : make_float4(0.f, 0.f, 0.f, 0.f);
        }
        __syncthreads();

        const float* A0 = sA + rg*6*Dc;
        float acc[6][4] = {};
        #pragma unroll 2
        for (int k = 0; k < Dc; k += 4) {
            float4 b0 = *(const float4*)(sB + (k+0)*Dc + c0);
            float4 b1 = *(const float4*)(sB + (k+1)*Dc + c0);
            float4 b2 = *(const float4*)(sB + (k+2)*Dc + c0);
            float4 b3 = *(const float4*)(sB + (k+3)*Dc + c0);
            #pragma unroll
            for (int r = 0; r < 6; ++r) {
                float4 a = *(const float4*)(A0 + r*Dc + k);
                acc[r][0] = fmaf(a.w,b3.x,fmaf(a.z,b2.x,fmaf(a.y,b1.x,fmaf(a.x,b0.x,acc[r][0]))));
                acc[r][1] = fmaf(a.w,b3.y,fmaf(a.z,b2.y,fmaf(a.y,b1.y,fmaf(a.x,b0.y,acc[r][1]))));
                acc[r][2] = fmaf(a.w,b3.z,fmaf(a.z,b2.z,fmaf(a.y,b1.z,fmaf(a.x,b0.z,acc[r][2]))));
                acc[r][3] = fmaf(a.w,b3.w,fmaf(a.z,b2.w,fmaf(a.y,b1.w,fmaf(a.x,b0.w,acc[r][3]))));
            }
        }
        #pragma unroll
        for (int r = 0; r < 6; ++r) {
            float4 v;
            v.x = acc[r][0] + sBias[c0+0];
            v.y = acc[r][1] + sBias[c0+1];
            v.z = acc[r][2] + sBias[c0+2];
            v.w = acc[r][3] + sBias[c0+3];
            *(float4*)(outp + (r0 + rg*6 + r)*Dc + c0) = v;
        }
    }
}

// ---------- phase 2: logits + softmax + aggregation + residual + LN ----------
// block = (b, k, i-half); 512 threads = 8 waves; wave owns 3 i's. 69.5 KB LDS -> 2 blocks/CU.
__global__ __launch_bounds__(GT) void k_p2(
    const float* __restrict__ h,
    const float* __restrict__ hip_ws, const float* __restrict__ hjp_ws,
    const float* __restrict__ msg_ws,
    const float* __restrict__ wa2, const float* __restrict__ gamma,
    const float* __restrict__ beta, float* __restrict__ out)
{
    const int blk = blockIdx.x;
    const int b  = blk >> 6;
    const int k  = (blk >> 1) & 31;
    const int i0 = (blk & 1) * 24;

    __shared__ float HJ[48*132];
    __shared__ float MS[48*132];
    __shared__ float HI[24*132];
    __shared__ float WA[Dc];
    __shared__ float GM[Dc];
    __shared__ float BT[Dc];
    __shared__ float WT[24*48];

    const int tid = threadIdx.x;

    for (int idx = tid; idx < 48*32; idx += GT) {
        const int j = idx >> 5, c4 = (idx & 31) * 4;
        const int g = ((b*Lc + j)*Kc + k)*Dc + c4;
        *(float4*)(HJ + j*132 + c4) = *(const float4*)(hjp_ws + g);
        *(float4*)(MS + j*132 + c4) = *(const float4*)(msg_ws + g);
    }
    for (int idx = tid; idx < 24*32; idx += GT) {
        const int i = idx >> 5, c4 = (idx & 31) * 4;
        const int g = ((b*Lc + i0 + i)*Kc + k)*Dc + c4;
        *(float4*)(HI + i*132 + c4) = *(const float4*)(hip_ws + g);
    }
    if (tid < 32)       ((float4*)WA)[tid]      = ((const float4*)wa2)[tid];
    else if (tid < 64)  ((float4*)GM)[tid - 32] = ((const float4*)gamma)[tid - 32];
    else if (tid < 96)  ((float4*)BT)[tid - 64] = ((const float4*)beta)[tid - 64];
    __syncthreads();

    const int wave = tid >> 6;
    const int lane = tid & 63;
    const int il0  = wave * 3;
    const bool jv  = lane < 48;
    const int  jl  = jv ? lane : 0;

    float s0 = 0.f, s1 = 0.f, s2 = 0.f;
    {
        const float* hj = HJ + jl*132;
        const float* hA = HI + il0*132;
        const float* hB = hA + 132;
        const float* hC = hB + 132;
        #pragma unroll 4
        for (int d = 0; d < Dc; d += 4) {
            const float4 hj4 = *(const float4*)(hj + d);
            const float4 w4  = *(const float4*)(WA + d);
            const float4 a4  = *(const float4*)(hA + d);
            const float4 b4  = *(const float4*)(hB + d);
            const float4 c4  = *(const float4*)(hC + d);
            s0 = fmaf(fmaxf(a4.x + hj4.x, 0.f), w4.x, s0);
            s0 = fmaf(fmaxf(a4.y + hj4.y, 0.f), w4.y, s0);
            s0 = fmaf(fmaxf(a4.z + hj4.z, 0.f), w4.z, s0);
            s0 = fmaf(fmaxf(a4.w + hj4.w, 0.f), w4.w, s0);
            s1 = fmaf(fmaxf(b4.x + hj4.x, 0.f), w4.x, s1);
            s1 = fmaf(fmaxf(b4.y + hj4.y, 0.f), w4.y, s1);
            s1 = fmaf(fmaxf(b4.z + hj4.z, 0.f), w4.z, s1);
            s1 = fmaf(fmaxf(b4.w + hj4.w, 0.f), w4.w, s1);
            s2 = fmaf(fmaxf(c4.x + hj4.x, 0.f), w4.x, s2);
            s2 = fmaf(fmaxf(c4.y + hj4.y, 0.f), w4.y, s2);
            s2 = fmaf(fmaxf(c4.z + hj4.z, 0.f), w4.z, s2);
            s2 = fmaf(fmaxf(c4.w + hj4.w, 0.f), w4.w, s2);
        }
    }

    float sv[3] = { jv ? s0 : -1e30f, jv ? s1 : -1e30f, jv ? s2 : -1e30f };
    #pragma unroll
    for (int q = 0; q < 3; ++q) {
        float m = sv[q];
        #pragma unroll
        for (int off = 32; off; off >>= 1) m = fmaxf(m, __shfl_xor(m, off));
        const float p = jv ? __expf(sv[q] - m) : 0.f;
        float sum = p;
        #pragma unroll
        for (int off = 32; off; off >>= 1) sum += __shfl_xor(sum, off);
        if (jv) WT[(il0 + q)*48 + lane] = p / sum;
    }
    __syncthreads();

    const int d0 = lane * 2;
    float ac[3][2] = {};
    const float* wt0 = WT + il0*48;
    const float* wt1 = wt0 + 48;
    const float* wt2 = wt1 + 48;
    #pragma unroll 4
    for (int j = 0; j < 48; ++j) {
        const float2 m2 = *(const float2*)(MS + j*132 + d0);
        const float wA = wt0[j], wB = wt1[j], wC = wt2[j];
        ac[0][0] = fmaf(wA, m2.x, ac[0][0]); ac[0][1] = fmaf(wA, m2.y, ac[0][1]);
        ac[1][0] = fmaf(wB, m2.x, ac[1][0]); ac[1][1] = fmaf(wB, m2.y, ac[1][1]);
        ac[2][0] = fmaf(wC, m2.x, ac[2][0]); ac[2][1] = fmaf(wC, m2.y, ac[2][1]);
    }
    const float gm0 = GM[d0], gm1 = GM[d0+1], bt0 = BT[d0], bt1 = BT[d0+1];
    #pragma unroll
    for (int q = 0; q < 3; ++q) {
        const int i = i0 + il0 + q;
        const int g = ((b*Lc + i)*Kc + k)*Dc + d0;
        const float2 h2 = *(const float2*)(h + g);
        const float x0 = h2.x + ac[q][0];
        const float x1 = h2.y + ac[q][1];
        float ps = x0 + x1;
        float pq = x0*x0 + x1*x1;
        #pragma unroll
        for (int off = 32; off; off >>= 1) {
            ps += __shfl_xor(ps, off);
            pq += __shfl_xor(pq, off);
        }
        const float mu  = ps * (1.f/128.f);
        const float var = pq * (1.f/128.f) - mu*mu;
        const float rs  = rsqrtf(var + 1e-5f);
        float2 o2;
        o2.x = (x0 - mu)*rs*gm0 + bt0;
        o2.y = (x1 - mu)*rs*gm1 + bt1;
        *(float2*)(out + g) = o2;
    }
}

extern "C" void kernel_launch(void* const* d_in, const int* in_sizes, int n_in,
                              void* d_out, int out_size, void* d_ws, size_t ws_size,
                              hipStream_t stream)
{
    const float* h     = (const float*)d_in[0];
    const float* Wm1   = (const float*)d_in[1];
    const float* bm1   = (const float*)d_in[2];
    const float* Wm2   = (const float*)d_in[3];
    const float* bm2   = (const float*)d_in[4];
    const float* Wa1   = (const float*)d_in[5];
    const float* ba1   = (const float*)d_in[6];
    const float* wa2   = (const float*)d_in[7];
    // d_in[8] = ba2: softmax-invariant constant, dropped
    const float* gamma = (const float*)d_in[9];
    const float* beta  = (const float*)d_in[10];

    float* msg_ws = (float*)d_ws;
    float* hip_ws = msg_ws + ROWS*Dc;
    float* hjp_ws = hip_ws + ROWS*Dc;
    float* outp   = (float*)d_out;

    hipLaunchKernelGGL(k_p1, dim3(256), dim3(GT), 0, stream,
                       h, Wm1, bm1, Wm2, bm2, Wa1, ba1,
                       msg_ws, hip_ws, hjp_ws);
    hipLaunchKernelGGL(k_p2, dim3(Bc*Kc*2), dim3(GT), 0, stream,
                       h, hip_ws, hjp_ws, msg_ws, wa2, gamma, beta, outp);
}